// Round 1
// baseline (672.718 us; speedup 1.0000x reference)
//
#include <hip/hip_runtime.h>

#define NHEAD 8

// ---------------------------------------------------------------------------
// Kernel 1: count incoming edges per node (for CSR build).
// ---------------------------------------------------------------------------
__global__ __launch_bounds__(256) void count_kernel(
    const int* __restrict__ dst, int* __restrict__ cnt, int E)
{
    const int e = blockIdx.x * 256 + threadIdx.x;
    if (e < E) atomicAdd(&cnt[dst[e]], 1);
}

// ---------------------------------------------------------------------------
// Kernel 2: single-block exclusive prefix scan of cnt[N] -> offs[N+1],
// plus a cursor copy for the scatter pass. N=10000 fits 1024 threads x 10.
// ---------------------------------------------------------------------------
__global__ __launch_bounds__(1024) void scan_kernel(
    const int* __restrict__ cnt, int* __restrict__ offs,
    int* __restrict__ cursor, int n)
{
    __shared__ int sdata[1024];
    const int tid = threadIdx.x;
    const int items = (n + 1023) >> 10;   // 10 for n=10000
    const int base = tid * items;
    int local[16];
    int sum = 0;
    for (int i = 0; i < items && i < 16; ++i) {
        int idx = base + i;
        int v = (idx < n) ? cnt[idx] : 0;
        local[i] = sum;
        sum += v;
    }
    sdata[tid] = sum;
    __syncthreads();
    for (int off = 1; off < 1024; off <<= 1) {
        int v = (tid >= off) ? sdata[tid - off] : 0;
        __syncthreads();
        sdata[tid] += v;
        __syncthreads();
    }
    const int prev = (tid > 0) ? sdata[tid - 1] : 0;
    for (int i = 0; i < items && i < 16; ++i) {
        int idx = base + i;
        if (idx < n) {
            int o = prev + local[i];
            offs[idx] = o;
            cursor[idx] = o;
        }
    }
    if (tid == 0) offs[n] = sdata[1023];
}

// ---------------------------------------------------------------------------
// Kernel 3: scatter edge ids into CSR buckets.
// ---------------------------------------------------------------------------
__global__ __launch_bounds__(256) void scatter_kernel(
    const int* __restrict__ dst, int* __restrict__ cursor,
    int* __restrict__ eids, int E)
{
    const int e = blockIdx.x * 256 + threadIdx.x;
    if (e >= E) return;
    const int n = dst[e];
    const int p = atomicAdd(&cursor[n], 1);
    eids[p] = e;
}

// ---------------------------------------------------------------------------
// Kernel 4: FUSED logits + softmax + aggregation. One block (256 thr) per
// node. Post-scaling softmax: acc += exp(k.q/16)*v, dsum += exp(...); divide
// by dsum once at the end. Removes the exw round-trip, all denom atomics and
// the per-edge q gather (q read once per node, held in registers).
//
// Per 8-edge group:
//   phase A: wave w computes logits for edges g+w and g+w+4 (k-row loads,
//            8-lane xor-reduce per head, exp -> ex_s[buf], double-buffered)
//   single __syncthreads()
//   phase B: all 256 threads accumulate 8 edges, fully unrolled
//            (8 independent 4B loads in flight per thread).
// Thread t owns one output element: t<64 -> out0[m=t]; t>=64 -> out1 flat
// j=t-64 (m=j/3, c=j%3). Head h = m/8 = j/24.
// ---------------------------------------------------------------------------
__global__ __launch_bounds__(256) void fused_kernel(
    const float* __restrict__ k0, const float* __restrict__ k1,
    const float* __restrict__ q0, const float* __restrict__ q1,
    const float* __restrict__ v0, const float* __restrict__ v1,
    const int* __restrict__ offs, const int* __restrict__ eids,
    float* __restrict__ out, int N)
{
    __shared__ int   se[256];
    __shared__ float ex_s[2][8][NHEAD];
    __shared__ float ds_s[4][NHEAD];

    const int n    = blockIdx.x;
    const int t    = threadIdx.x;
    const int w    = t >> 6;       // wave id 0..3
    const int lane = t & 63;

    const int start = offs[n];
    const int end   = offs[n + 1];

    // q fragment for the dot phase, held in registers for the whole kernel.
    // All 4 waves load the same 1KB row -> L1 broadcast, ~10MB HBM total.
    const float  qv0 = q0[(size_t)n * 64 + lane];
    const float3 qv1 = *(const float3*)(q1 + (size_t)n * 192 + lane * 3);

    // v/out mapping for the accumulate phase
    const int j = t - 64;
    const int h = (t < 64) ? (t >> 3) : (j / 24);
    const float* vptr;
    int vstride;
    if (t < 64) { vptr = v0 + t; vstride = 64;  }
    else        { vptr = v1 + j; vstride = 192; }

    float acc  = 0.f;
    float dsum = 0.f;   // each lane accumulates its own head's denominator
    int buf = 0;

    for (int cb = start; cb < end; cb += 256) {
        const int c = min(256, end - cb);
        __syncthreads();                       // protect se from prev chunk's readers
        if (t < c) se[t] = eids[cb + t];
        __syncthreads();

        for (int g = 0; g < c; g += 8) {
            // ---- phase A: this wave's 2 logits -------------------------
            #pragma unroll
            for (int s = 0; s < 2; ++s) {
                const int idx = g + w + s * 4;
                float ex = 0.f;
                if (idx < c) {                 // wave-uniform branch
                    const int e = se[idx];
                    const float  kv0 = k0[(size_t)e * 64 + lane];
                    const float3 kv1 = *(const float3*)(k1 + (size_t)e * 192 + lane * 3);
                    float p = kv0 * qv0 + kv1.x * qv1.x + kv1.y * qv1.y
                            + kv1.z * qv1.z;
                    p += __shfl_xor(p, 1);     // reduce within 8-lane head group
                    p += __shfl_xor(p, 2);
                    p += __shfl_xor(p, 4);
                    // d_key = 256 -> scale 1/16. |logit| small; skip seg-max
                    // (softmax shift-invariant, exp cannot overflow here).
                    ex = __expf(p * 0.0625f);
                }
                if ((lane & 7) == 0) ex_s[buf][w + s * 4][lane >> 3] = ex;
                dsum += ex;                    // lane's head; one copy read later
            }
            __syncthreads();                   // ex_s[buf] ready (only barrier/group)

            // ---- phase B: accumulate 8 edges, 8 loads in flight --------
            const int gc = min(8, c - g);
            #pragma unroll
            for (int jj = 0; jj < 8; ++jj) {
                if (jj < gc) {                 // block-uniform branch
                    const int e = se[g + jj];
                    acc += ex_s[buf][jj][h] * vptr[(size_t)e * vstride];
                }
            }
            buf ^= 1;                          // WAR-safe: next A writes other buf
        }
    }

    // reduce per-wave denominators across the 4 waves
    if ((lane & 7) == 0) ds_s[w][lane >> 3] = dsum;
    __syncthreads();
    const float d = ds_s[0][h] + ds_s[1][h] + ds_s[2][h] + ds_s[3][h];
    const float invd = (end > start) ? (1.0f / d) : 0.0f;  // empty node -> 0
    acc *= invd;

    if (t < 64) out[(size_t)n * 64 + t] = acc;
    else        out[(size_t)N * 64 + (size_t)n * 192 + j] = acc;
}

extern "C" void kernel_launch(void* const* d_in, const int* in_sizes, int n_in,
                              void* d_out, int out_size, void* d_ws, size_t ws_size,
                              hipStream_t stream) {
    const float* v0 = (const float*)d_in[0];   // [E,64,1]
    const float* v1 = (const float*)d_in[1];   // [E,64,3]
    const float* k0 = (const float*)d_in[2];   // [E,64,1]
    const float* k1 = (const float*)d_in[3];   // [E,64,3]
    const float* q0 = (const float*)d_in[4];   // [N,64,1]
    const float* q1 = (const float*)d_in[5];   // [N,64,3]
    const int*  dst = (const int*)d_in[6];     // [E]

    const int E = in_sizes[6];
    const int N = in_sizes[4] / 64;

    // workspace layout (all small: ~1.4 MB)
    char* ws = (char*)d_ws;
    size_t off = 0;
    int* cnt = (int*)(ws + off);       off += (size_t)N * 4;
    int* offs = (int*)(ws + off);      off += (size_t)(N + 1) * 4;
    off = (off + 15) & ~(size_t)15;
    int* cursor = (int*)(ws + off);    off += (size_t)N * 4;
    off = (off + 15) & ~(size_t)15;
    int* eids = (int*)(ws + off);      off += (size_t)E * 4;

    hipMemsetAsync(cnt, 0, (size_t)N * 4, stream);

    count_kernel<<<(E + 255) / 256, 256, 0, stream>>>(dst, cnt, E);

    scan_kernel<<<1, 1024, 0, stream>>>(cnt, offs, cursor, N);

    scatter_kernel<<<(E + 255) / 256, 256, 0, stream>>>(dst, cursor, eids, E);

    fused_kernel<<<N, 256, 0, stream>>>(
        k0, k1, q0, q1, v0, v1, offs, eids, (float*)d_out, N);
}

// Round 2
// 643.478 us; speedup vs baseline: 1.0454x; 1.0454x over previous
//
#include <hip/hip_runtime.h>

#define NHEAD 8

// ---------------------------------------------------------------------------
// Kernel 1: count incoming edges per node (for CSR build).
// ---------------------------------------------------------------------------
__global__ __launch_bounds__(256) void count_kernel(
    const int* __restrict__ dst, int* __restrict__ cnt, int E)
{
    const int e = blockIdx.x * 256 + threadIdx.x;
    if (e < E) atomicAdd(&cnt[dst[e]], 1);
}

// ---------------------------------------------------------------------------
// Kernel 2: single-block exclusive prefix scan of cnt[N] -> offs[N+1],
// plus a cursor copy for the scatter pass. N=10000 fits 1024 threads x 10.
// ---------------------------------------------------------------------------
__global__ __launch_bounds__(1024) void scan_kernel(
    const int* __restrict__ cnt, int* __restrict__ offs,
    int* __restrict__ cursor, int n)
{
    __shared__ int sdata[1024];
    const int tid = threadIdx.x;
    const int items = (n + 1023) >> 10;   // 10 for n=10000
    const int base = tid * items;
    int local[16];
    int sum = 0;
    for (int i = 0; i < items && i < 16; ++i) {
        int idx = base + i;
        int v = (idx < n) ? cnt[idx] : 0;
        local[i] = sum;
        sum += v;
    }
    sdata[tid] = sum;
    __syncthreads();
    for (int off = 1; off < 1024; off <<= 1) {
        int v = (tid >= off) ? sdata[tid - off] : 0;
        __syncthreads();
        sdata[tid] += v;
        __syncthreads();
    }
    const int prev = (tid > 0) ? sdata[tid - 1] : 0;
    for (int i = 0; i < items && i < 16; ++i) {
        int idx = base + i;
        if (idx < n) {
            int o = prev + local[i];
            offs[idx] = o;
            cursor[idx] = o;
        }
    }
    if (tid == 0) offs[n] = sdata[1023];
}

// ---------------------------------------------------------------------------
// Kernel 3: scatter edge ids into CSR buckets.
// ---------------------------------------------------------------------------
__global__ __launch_bounds__(256) void scatter_kernel(
    const int* __restrict__ dst, int* __restrict__ cursor,
    int* __restrict__ eids, int E)
{
    const int e = blockIdx.x * 256 + threadIdx.x;
    if (e >= E) return;
    const int n = dst[e];
    const int p = atomicAdd(&cursor[n], 1);
    eids[p] = e;
}

// ---------------------------------------------------------------------------
// Kernel 4: FUSED logits + softmax + aggregation, restructured for explicit
// memory-level parallelism (round-1 version compiled to VGPR=20 => compiler
// serialized every gather load; 1.56 TB/s latency-bound).
//
// One block (256 thr) per node. Per 16-edge group:
//   phase A: wave w owns edges g+4w..g+4w+3. k-rows loaded into explicit
//            reg arrays FIRST (8 wide loads in flight), then 8-lane
//            xor-reduce, exp -> ex_s[buf] (double-buffered, 1 barrier/group).
//   phase B: edge ids via 4x int4 LDS reads; 16 independent v loads into
//            vv[16]; 16 FMAs against ex_s read as 4x float4.
// se is clamp-filled to all 256 slots so inner loops are branch-free and
// every load is in-bounds; padded edges contribute ex=0.
// Thread t owns one output element: t<64 -> out0[m=t]; t>=64 -> out1 flat
// j=t-64 (m=j/3, c=j%3). Head h = m/8 = j/24.
// ---------------------------------------------------------------------------
__global__ __launch_bounds__(256) void fused_kernel(
    const float* __restrict__ k0, const float* __restrict__ k1,
    const float* __restrict__ q0, const float* __restrict__ q1,
    const float* __restrict__ v0, const float* __restrict__ v1,
    const int* __restrict__ offs, const int* __restrict__ eids,
    float* __restrict__ out, int N)
{
    __shared__ int   se[256];
    __shared__ float ex_s[2][NHEAD][16];   // [buf][head][edge-in-group]
    __shared__ float ds_s[4][NHEAD];

    const int n    = blockIdx.x;
    const int t    = threadIdx.x;
    const int w    = t >> 6;       // wave id 0..3
    const int lane = t & 63;

    const int start = offs[n];
    const int end   = offs[n + 1];

    // q fragment held in registers for the whole kernel (L1-broadcast read).
    const float  qv0 = q0[(size_t)n * 64 + lane];
    const float3 qv1 = *(const float3*)(q1 + (size_t)n * 192 + lane * 3);

    // v/out mapping for the accumulate phase
    const int j = t - 64;
    const int h = (t < 64) ? (t >> 3) : (j / 24);
    const float* vptr;
    int vstride;
    if (t < 64) { vptr = v0 + t; vstride = 64;  }
    else        { vptr = v1 + j; vstride = 192; }

    float acc  = 0.f;
    float dsum = 0.f;   // this lane's head, this wave's edges
    int buf = 0;

    for (int cb = start; cb < end; cb += 256) {
        const int c = min(256, end - cb);
        __syncthreads();                       // protect se from prev chunk
        se[t] = eids[cb + min(t, c - 1)];      // clamp-fill all 256 slots
        __syncthreads();

        for (int g = 0; g < c; g += 16) {
            // ---- phase A: this wave's 4 logits, loads batched first ----
            float  a0[4];
            float3 a1[4];
            #pragma unroll
            for (int s = 0; s < 4; ++s) {
                const int e = se[g + w * 4 + s];
                a0[s] = k0[(size_t)e * 64 + lane];
                a1[s] = *(const float3*)(k1 + (size_t)e * 192 + lane * 3);
            }
            #pragma unroll
            for (int s = 0; s < 4; ++s) {
                float p = a0[s] * qv0 + a1[s].x * qv1.x + a1[s].y * qv1.y
                        + a1[s].z * qv1.z;
                p += __shfl_xor(p, 1);         // reduce within 8-lane head grp
                p += __shfl_xor(p, 2);
                p += __shfl_xor(p, 4);
                // d_key = 256 -> scale 1/16. |logit| small; skip seg-max
                // (softmax shift-invariant, exp cannot overflow here).
                const float ex = (g + w * 4 + s < c) ? __expf(p * 0.0625f)
                                                     : 0.f;
                if ((lane & 7) == 0) ex_s[buf][lane >> 3][w * 4 + s] = ex;
                dsum += ex;
            }
            __syncthreads();                   // ex_s[buf] ready (1/group)

            // ---- phase B: 16 independent v loads in flight -------------
            const int4 e0 = *(const int4*)&se[g];
            const int4 e1 = *(const int4*)&se[g + 4];
            const int4 e2 = *(const int4*)&se[g + 8];
            const int4 e3 = *(const int4*)&se[g + 12];
            float vv[16];
            vv[0]  = vptr[(size_t)e0.x * vstride];
            vv[1]  = vptr[(size_t)e0.y * vstride];
            vv[2]  = vptr[(size_t)e0.z * vstride];
            vv[3]  = vptr[(size_t)e0.w * vstride];
            vv[4]  = vptr[(size_t)e1.x * vstride];
            vv[5]  = vptr[(size_t)e1.y * vstride];
            vv[6]  = vptr[(size_t)e1.z * vstride];
            vv[7]  = vptr[(size_t)e1.w * vstride];
            vv[8]  = vptr[(size_t)e2.x * vstride];
            vv[9]  = vptr[(size_t)e2.y * vstride];
            vv[10] = vptr[(size_t)e2.z * vstride];
            vv[11] = vptr[(size_t)e2.w * vstride];
            vv[12] = vptr[(size_t)e3.x * vstride];
            vv[13] = vptr[(size_t)e3.y * vstride];
            vv[14] = vptr[(size_t)e3.z * vstride];
            vv[15] = vptr[(size_t)e3.w * vstride];

            const float4 w0 = *(const float4*)&ex_s[buf][h][0];
            const float4 w1 = *(const float4*)&ex_s[buf][h][4];
            const float4 w2 = *(const float4*)&ex_s[buf][h][8];
            const float4 w3 = *(const float4*)&ex_s[buf][h][12];

            acc += w0.x * vv[0];
            acc += w0.y * vv[1];
            acc += w0.z * vv[2];
            acc += w0.w * vv[3];
            acc += w1.x * vv[4];
            acc += w1.y * vv[5];
            acc += w1.z * vv[6];
            acc += w1.w * vv[7];
            acc += w2.x * vv[8];
            acc += w2.y * vv[9];
            acc += w2.z * vv[10];
            acc += w2.w * vv[11];
            acc += w3.x * vv[12];
            acc += w3.y * vv[13];
            acc += w3.z * vv[14];
            acc += w3.w * vv[15];

            buf ^= 1;                          // WAR-safe double buffer
        }
    }

    // reduce per-wave denominators across the 4 waves
    if ((lane & 7) == 0) ds_s[w][lane >> 3] = dsum;
    __syncthreads();
    const float d = ds_s[0][h] + ds_s[1][h] + ds_s[2][h] + ds_s[3][h];
    const float invd = (end > start) ? (1.0f / d) : 0.0f;  // empty node -> 0
    acc *= invd;

    if (t < 64) out[(size_t)n * 64 + t] = acc;
    else        out[(size_t)N * 64 + (size_t)n * 192 + j] = acc;
}

extern "C" void kernel_launch(void* const* d_in, const int* in_sizes, int n_in,
                              void* d_out, int out_size, void* d_ws, size_t ws_size,
                              hipStream_t stream) {
    const float* v0 = (const float*)d_in[0];   // [E,64,1]
    const float* v1 = (const float*)d_in[1];   // [E,64,3]
    const float* k0 = (const float*)d_in[2];   // [E,64,1]
    const float* k1 = (const float*)d_in[3];   // [E,64,3]
    const float* q0 = (const float*)d_in[4];   // [N,64,1]
    const float* q1 = (const float*)d_in[5];   // [N,64,3]
    const int*  dst = (const int*)d_in[6];     // [E]

    const int E = in_sizes[6];
    const int N = in_sizes[4] / 64;

    // workspace layout (all small: ~1.4 MB)
    char* ws = (char*)d_ws;
    size_t off = 0;
    int* cnt = (int*)(ws + off);       off += (size_t)N * 4;
    int* offs = (int*)(ws + off);      off += (size_t)(N + 1) * 4;
    off = (off + 15) & ~(size_t)15;
    int* cursor = (int*)(ws + off);    off += (size_t)N * 4;
    off = (off + 15) & ~(size_t)15;
    int* eids = (int*)(ws + off);      off += (size_t)E * 4;

    hipMemsetAsync(cnt, 0, (size_t)N * 4, stream);

    count_kernel<<<(E + 255) / 256, 256, 0, stream>>>(dst, cnt, E);

    scan_kernel<<<1, 1024, 0, stream>>>(cnt, offs, cursor, N);

    scatter_kernel<<<(E + 255) / 256, 256, 0, stream>>>(dst, cursor, eids, E);

    fused_kernel<<<N, 256, 0, stream>>>(
        k0, k1, q0, q1, v0, v1, offs, eids, (float*)d_out, N);
}